// Round 3
// baseline (339.228 us; speedup 1.0000x reference)
//
#include <hip/hip_runtime.h>

// SESConv via implicit GEMM, mfma_f32_32x32x16_bf16, M = 2 r-neighbor gs x 16 o.
// x: (8,16,12,128,128) f32; weight: (16,16,4,9) f32; basis: (9,12,5,5) f32; out same shape as x-out.

#define HW 128
#define IMG (HW*HW)
#define ICSTR (12*IMG)          // floats between input channels
#define TILE 16
#define HALO 20
#define NPX (HALO*HALO)         // 400
#define PLANEB (NPX*16)         // 6400 B per k-half plane

typedef __bf16  bf16x8 __attribute__((ext_vector_type(8)));
typedef float   f32x16 __attribute__((ext_vector_type(16)));

__device__ __forceinline__ unsigned short f2bf(float f) {
    unsigned u = __builtin_bit_cast(unsigned, f);
    u += 0x7fffu + ((u >> 16) & 1u);
    return (unsigned short)(u >> 16);
}

// A-panel: frag[(((P*3+rridx)*3+ss)*2+s0sel)*25+tap][lane(64)][j(8)] bf16 (1KB/frag, 900KB)
// A[m][k]: m=lane&31 = r0sel*16+o, k=(lane>>5)*8+j = ic. Invalid rows/frags -> 0.
__global__ void build_kc2(const float* __restrict__ wgt, const float* __restrict__ basis,
                          unsigned short* __restrict__ kc2) {
    int idx = blockIdx.x * 256 + threadIdx.x;
    const int total = 2 * 3 * 3 * 2 * 25 * 64 * 8;   // 460800
    if (idx >= total) return;
    int j    = idx & 7;
    int lane = (idx >> 3) & 63;
    int fr   = idx >> 9;
    int tap  = fr % 25;  int r1 = fr / 25;
    int s0sel = r1 & 1;  int r2 = r1 >> 1;
    int ss   = r2 % 3;   int r3 = r2 / 3;
    int rridx = r3 % 3;  int P  = r3 / 3;
    int m = lane & 31, khalf = lane >> 5;
    int ic = khalf * 8 + j;
    int o = m & 15, r0sel = m >> 4;
    int s0 = ss - 1 + s0sel;
    int rr = (2 * P + rridx) & 3;
    int r0 = 2 * P + r0sel;
    int i  = (rr - r0) & 3;
    float s = 0.f;
    if (s0 >= 0 && s0 <= 2 && i <= 1) {
        int jj = 1 - s0sel;
        int rbase = 2 * i + jj;
        int g_out = r0 * 3 + s0;
        int xk = tap / 5, yk = tap % 5;
        #pragma unroll
        for (int f = 0; f < 9; ++f)
            s = fmaf(wgt[((o * 16 + ic) * 4 + rbase) * 9 + f],
                     basis[((f * 12 + g_out) * 5 + xk) * 5 + yk], s);
    }
    kc2[idx] = f2bf(s);
}

__global__ __launch_bounds__(256, 3)
void conv32(const float* __restrict__ x, const unsigned short* __restrict__ kc2,
            float* __restrict__ out) {
    const int b    = blockIdx.z;
    const int P    = blockIdx.y;              // r-pair: r0 in {2P, 2P+1}
    const int tile = blockIdx.x;
    const int th0  = (tile >> 3) * TILE;
    const int tw0  = (tile & 7) * TILE;

    const int t     = threadIdx.x;
    const int lane  = t & 63;
    const int wave  = t >> 6;
    const int n     = lane & 31;              // B/D column (pixel in group)
    const int khalf = lane >> 5;

    __shared__ uint4 xs4[2 * PLANEB / 16];    // 12800 B: [khalf][px(400)][8ic]
    char* xsc = (char*)xs4;

    const int laneoff = khalf * PLANEB + (((n >> 4) * HALO) + (n & 15)) * 16;

    f32x16 acc[3][2];
    #pragma unroll
    for (int s0 = 0; s0 < 3; ++s0)
        #pragma unroll
        for (int g = 0; g < 2; ++g)
            #pragma unroll
            for (int r = 0; r < 16; ++r) acc[s0][g][r] = 0.f;

    #pragma unroll
    for (int sidx = 0; sidx < 9; ++sidx) {
        const int rridx = sidx / 3;
        const int ss    = sidx % 3;
        const int rr    = (2 * P + rridx) & 3;
        const int g_in  = rr * 3 + ss;
        const float* xb = x + ((size_t)b * 16 * 12 + g_in) * IMG;

        __syncthreads();
        // stage 20x20 halo, 16 ic, fp32 -> bf16, two k-half planes
        for (int p = t; p < NPX; p += 256) {
            int hr = p / HALO, hc = p - hr * HALO;
            int hh = th0 + hr - 2, ww = tw0 + hc - 2;
            bool ok = ((unsigned)hh < 128u) && ((unsigned)ww < 128u);
            const float* px = xb + hh * HW + ww;
            unsigned short v[16];
            #pragma unroll
            for (int ic = 0; ic < 16; ++ic) {
                float f = ok ? px[(size_t)ic * ICSTR] : 0.f;
                v[ic] = f2bf(f);
            }
            uint4 lo, hi;
            lo.x = v[0] | (v[1] << 16);   lo.y = v[2] | (v[3] << 16);
            lo.z = v[4] | (v[5] << 16);   lo.w = v[6] | (v[7] << 16);
            hi.x = v[8] | (v[9] << 16);   hi.y = v[10] | (v[11] << 16);
            hi.z = v[12] | (v[13] << 16); hi.w = v[14] | (v[15] << 16);
            *(uint4*)(xsc + p * 16)          = lo;
            *(uint4*)(xsc + PLANEB + p * 16) = hi;
        }
        __syncthreads();

        const int frag0 = (((P * 3 + rridx) * 3 + ss) * 2) * 25;   // s0sel=0 base
        const unsigned short* kp = kc2 + (size_t)frag0 * 512 + lane * 8;

        #pragma unroll
        for (int xk = 0; xk < 5; ++xk) {
            #pragma unroll
            for (int yk = 0; yk < 5; ++yk) {
                const int tap = xk * 5 + yk;
                bf16x8 a0, a1;
                if (ss >= 1) a0 = *(const bf16x8*)(kp + (size_t)tap * 512);
                a1 = *(const bf16x8*)(kp + (size_t)(25 + tap) * 512);
                #pragma unroll
                for (int grp = 0; grp < 2; ++grp) {
                    const int gidx = 2 * wave + grp;          // pixel group: tile rows 2g..2g+1
                    bf16x8 bfrag = *(const bf16x8*)(xsc + laneoff +
                                     (((2 * gidx + xk) * HALO) + yk) * 16);
                    if (ss >= 1)
                        acc[ss - 1][grp] = __builtin_amdgcn_mfma_f32_32x32x16_bf16(
                            a0, bfrag, acc[ss - 1][grp], 0, 0, 0);
                    acc[ss][grp] = __builtin_amdgcn_mfma_f32_32x32x16_bf16(
                        a1, bfrag, acc[ss][grp], 0, 0, 0);
                }
            }
        }
    }

    // epilogue: D col = n (pixel), row m = (reg&3) + 8*(reg>>2) + 4*khalf; m = r0sel*16+o
    #pragma unroll
    for (int s0 = 0; s0 < 3; ++s0) {
        #pragma unroll
        for (int grp = 0; grp < 2; ++grp) {
            const int gidx = 2 * wave + grp;
            const int h = th0 + 2 * gidx + (n >> 4);
            const int w = tw0 + (n & 15);
            #pragma unroll
            for (int reg = 0; reg < 16; ++reg) {
                int m = (reg & 3) + 8 * (reg >> 2) + 4 * khalf;
                int o = m & 15, r0sel = m >> 4;
                int g_out = (2 * P + r0sel) * 3 + s0;
                out[((size_t)(b * 16 + o) * 12 + g_out) * IMG + h * HW + w] =
                    acc[s0][grp][reg];
            }
        }
    }
}

extern "C" void kernel_launch(void* const* d_in, const int* in_sizes, int n_in,
                              void* d_out, int out_size, void* d_ws, size_t ws_size,
                              hipStream_t stream) {
    const float* x      = (const float*)d_in[0];
    const float* weight = (const float*)d_in[1];
    const float* basis  = (const float*)d_in[2];
    float* out = (float*)d_out;
    unsigned short* kc2 = (unsigned short*)d_ws;    // 921600 B

    build_kc2<<<dim3(460800 / 256), dim3(256), 0, stream>>>(weight, basis, kc2);
    conv32<<<dim3(64, 2, 8), dim3(256), 0, stream>>>(x, kc2, out);
}

// Round 4
// 293.767 us; speedup vs baseline: 1.1548x; 1.1548x over previous
//
#include <hip/hip_runtime.h>

// SESConv via implicit GEMM, mfma_f32_32x32x16_bf16, M = 2 r-neighbor gs x 16 o.
// R4: software-pipelined — double-buffered LDS staging (global loads overlap compute)
//     + A-frag prefetch depth 2, B-frag prefetch depth 1 in the tap loop.
// x: (8,16,12,128,128) f32; weight: (16,16,4,9) f32; basis: (9,12,5,5) f32.

#define HW 128
#define IMG (HW*HW)
#define ICSTR (12*IMG)          // floats between input channels
#define TILE 16
#define HALO 20
#define NPX (HALO*HALO)         // 400
#define PLANEB (NPX*16)         // 6400 B per k-half plane
#define BUFB (2*PLANEB)         // 12800 B per slice buffer

typedef __bf16  bf16x8 __attribute__((ext_vector_type(8)));
typedef float   f32x16 __attribute__((ext_vector_type(16)));

__device__ __forceinline__ unsigned short f2bf(float f) {
    unsigned u = __builtin_bit_cast(unsigned, f);
    u += 0x7fffu + ((u >> 16) & 1u);
    return (unsigned short)(u >> 16);
}

// A-panel: frag[(((P*3+rridx)*3+ss)*2+s0sel)*25+tap][lane(64)][j(8)] bf16 (1KB/frag)
// A[m][k]: m=lane&31 = r0sel*16+o, k=(lane>>5)*8+j = ic. Invalid rows/frags -> 0.
__global__ void build_kc2(const float* __restrict__ wgt, const float* __restrict__ basis,
                          unsigned short* __restrict__ kc2) {
    int idx = blockIdx.x * 256 + threadIdx.x;
    const int total = 2 * 3 * 3 * 2 * 25 * 64 * 8;   // 460800
    if (idx >= total) return;
    int j    = idx & 7;
    int lane = (idx >> 3) & 63;
    int fr   = idx >> 9;
    int tap  = fr % 25;  int r1 = fr / 25;
    int s0sel = r1 & 1;  int r2 = r1 >> 1;
    int ss   = r2 % 3;   int r3 = r2 / 3;
    int rridx = r3 % 3;  int P  = r3 / 3;
    int m = lane & 31, khalf = lane >> 5;
    int ic = khalf * 8 + j;
    int o = m & 15, r0sel = m >> 4;
    int s0 = ss - 1 + s0sel;
    int rr = (2 * P + rridx) & 3;
    int r0 = 2 * P + r0sel;
    int i  = (rr - r0) & 3;
    float s = 0.f;
    if (s0 >= 0 && s0 <= 2 && i <= 1) {
        int jj = 1 - s0sel;
        int rbase = 2 * i + jj;
        int g_out = r0 * 3 + s0;
        int xk = tap / 5, yk = tap % 5;
        #pragma unroll
        for (int f = 0; f < 9; ++f)
            s = fmaf(wgt[((o * 16 + ic) * 4 + rbase) * 9 + f],
                     basis[((f * 12 + g_out) * 5 + xk) * 5 + yk], s);
    }
    kc2[idx] = f2bf(s);
}

__device__ __forceinline__ void slice_loads(const float* __restrict__ xb,
                                            int th0, int tw0, int p, float* raw) {
    int hr = p / HALO, hc = p - hr * HALO;
    int hh = th0 + hr - 2, ww = tw0 + hc - 2;
    if (((unsigned)hh < 128u) && ((unsigned)ww < 128u)) {
        const float* px = xb + hh * HW + ww;
        #pragma unroll
        for (int ic = 0; ic < 16; ++ic) raw[ic] = px[(size_t)ic * ICSTR];
    } else {
        #pragma unroll
        for (int ic = 0; ic < 16; ++ic) raw[ic] = 0.f;
    }
}

__device__ __forceinline__ void cvt_write(char* __restrict__ dst, int p, const float* raw) {
    unsigned short v[16];
    #pragma unroll
    for (int ic = 0; ic < 16; ++ic) v[ic] = f2bf(raw[ic]);
    uint4 lo, hi;
    lo.x = v[0] | (v[1] << 16);   lo.y = v[2] | (v[3] << 16);
    lo.z = v[4] | (v[5] << 16);   lo.w = v[6] | (v[7] << 16);
    hi.x = v[8] | (v[9] << 16);   hi.y = v[10] | (v[11] << 16);
    hi.z = v[12] | (v[13] << 16); hi.w = v[14] | (v[15] << 16);
    *(uint4*)(dst + p * 16)          = lo;
    *(uint4*)(dst + PLANEB + p * 16) = hi;
}

__global__ __launch_bounds__(256, 2)
void conv32p(const float* __restrict__ x, const unsigned short* __restrict__ kc2,
             float* __restrict__ out) {
    const int b    = blockIdx.z;
    const int P    = blockIdx.y;
    const int tile = blockIdx.x;
    const int th0  = (tile >> 3) * TILE;
    const int tw0  = (tile & 7) * TILE;

    const int t     = threadIdx.x;
    const int lane  = t & 63;
    const int wave  = t >> 6;
    const int n     = lane & 31;
    const int khalf = lane >> 5;

    __shared__ uint4 xs4[2 * BUFB / 16];      // 25600 B (two slice buffers)
    char* xsc = (char*)xs4;

    const int laneoff = khalf * PLANEB + ((n >> 4) * HALO + (n & 15)) * 16;
    const int p0 = t, p1 = t + 256;
    const bool have1 = (p1 < NPX);

    f32x16 acc[3][2];
    #pragma unroll
    for (int s0 = 0; s0 < 3; ++s0)
        #pragma unroll
        for (int g = 0; g < 2; ++g)
            #pragma unroll
            for (int r = 0; r < 16; ++r) acc[s0][g][r] = 0.f;

    float raw0[16], raw1[16];

    // xb for slice sidx
    #define XB(sidx) (x + ((size_t)b * 192 + (((2 * P + (sidx) / 3) & 3) * 3 + (sidx) % 3)) * IMG)

    // prologue: stage slice 0
    slice_loads(XB(0), th0, tw0, p0, raw0);
    if (have1) slice_loads(XB(0), th0, tw0, p1, raw1);
    cvt_write(xsc, p0, raw0);
    if (have1) cvt_write(xsc, p1, raw1);
    __syncthreads();

    #pragma unroll
    for (int sidx = 0; sidx < 9; ++sidx) {
        const int rridx = sidx / 3;
        const int ss    = sidx % 3;
        char* buf = xsc + (sidx & 1) * BUFB;

        // issue next slice's global loads now; compute below hides the latency
        if (sidx < 8) {
            const float* xbn = XB(sidx + 1);
            slice_loads(xbn, th0, tw0, p0, raw0);
            if (have1) slice_loads(xbn, th0, tw0, p1, raw1);
        }

        const int frag0 = (((P * 3 + rridx) * 3 + ss) * 2) * 25;
        const unsigned short* kp = kc2 + (size_t)frag0 * 512 + lane * 8;

        bf16x8 a0[2], a1[2], bcur[2], bnext[2];
        if (ss >= 1) a0[0] = *(const bf16x8*)(kp + (size_t)0 * 512);
        a1[0] = *(const bf16x8*)(kp + (size_t)25 * 512);
        if (ss >= 1) a0[1] = *(const bf16x8*)(kp + (size_t)1 * 512);
        a1[1] = *(const bf16x8*)(kp + (size_t)26 * 512);
        #pragma unroll
        for (int grp = 0; grp < 2; ++grp)
            bcur[grp] = *(const bf16x8*)(buf + laneoff +
                          ((2 * (2 * wave + grp)) * HALO) * 16);

        #pragma unroll
        for (int tap = 0; tap < 25; ++tap) {
            // prefetch B for tap+1
            if (tap < 24) {
                const int nxk = (tap + 1) / 5, nyk = (tap + 1) % 5;
                #pragma unroll
                for (int grp = 0; grp < 2; ++grp)
                    bnext[grp] = *(const bf16x8*)(buf + laneoff +
                                   ((2 * (2 * wave + grp) + nxk) * HALO + nyk) * 16);
            }
            // MFMAs for tap
            #pragma unroll
            for (int grp = 0; grp < 2; ++grp) {
                if (ss >= 1)
                    acc[ss - 1][grp] = __builtin_amdgcn_mfma_f32_32x32x16_bf16(
                        a0[tap & 1], bcur[grp], acc[ss - 1][grp], 0, 0, 0);
                acc[ss][grp] = __builtin_amdgcn_mfma_f32_32x32x16_bf16(
                    a1[tap & 1], bcur[grp], acc[ss][grp], 0, 0, 0);
            }
            // prefetch A for tap+2 (into the slot just consumed)
            if (tap < 23) {
                if (ss >= 1) a0[tap & 1] = *(const bf16x8*)(kp + (size_t)(tap + 2) * 512);
                a1[tap & 1] = *(const bf16x8*)(kp + (size_t)(25 + tap + 2) * 512);
            }
            bcur[0] = bnext[0]; bcur[1] = bnext[1];
        }

        // publish next slice into the other buffer
        if (sidx < 8) {
            __syncthreads();
            char* nbuf = xsc + ((sidx + 1) & 1) * BUFB;
            cvt_write(nbuf, p0, raw0);
            if (have1) cvt_write(nbuf, p1, raw1);
            __syncthreads();
        }
    }
    #undef XB

    // epilogue: D col = n (pixel), row m = (reg&3) + 8*(reg>>2) + 4*khalf; m = r0sel*16+o
    #pragma unroll
    for (int s0 = 0; s0 < 3; ++s0) {
        #pragma unroll
        for (int grp = 0; grp < 2; ++grp) {
            const int gidx = 2 * wave + grp;
            const int h = th0 + 2 * gidx + (n >> 4);
            const int w = tw0 + (n & 15);
            #pragma unroll
            for (int reg = 0; reg < 16; ++reg) {
                int m = (reg & 3) + 8 * (reg >> 2) + 4 * khalf;
                int o = m & 15, r0sel = m >> 4;
                int g_out = (2 * P + r0sel) * 3 + s0;
                out[((size_t)(b * 16 + o) * 12 + g_out) * IMG + h * HW + w] =
                    acc[s0][grp][reg];
            }
        }
    }
}

extern "C" void kernel_launch(void* const* d_in, const int* in_sizes, int n_in,
                              void* d_out, int out_size, void* d_ws, size_t ws_size,
                              hipStream_t stream) {
    const float* x      = (const float*)d_in[0];
    const float* weight = (const float*)d_in[1];
    const float* basis  = (const float*)d_in[2];
    float* out = (float*)d_out;
    unsigned short* kc2 = (unsigned short*)d_ws;    // 921600 B

    build_kc2<<<dim3(460800 / 256), dim3(256), 0, stream>>>(weight, basis, kc2);
    conv32p<<<dim3(64, 2, 8), dim3(256), 0, stream>>>(x, kc2, out);
}